// Round 15
// baseline (4390.155 us; speedup 1.0000x reference)
//
#include <hip/hip_runtime.h>
#include <math.h>

// LSTM forward: T=1024, B=64, I=256, H=512 (4H=2048), fp32 in/out.
// Round 15: R14 verbatim EXCEPT the row-group barrier:
//   * R14: 64 blocks/group atomicAdd ONE address/step -> same-address RMW
//     serialization at the IF$ (~40-80cy each, ~4-5K cy/step suspected).
//   * R15: per-block epoch flag (plain coherent store, 16B stride); consumer
//     wave0 polls all 64 flags IN PARALLEL (lane=cg) with relaxed-agent
//     loads, exits on __all(flag >= t+1). Zero atomic contention.
//   Release chain unchanged (R6-verified): h stores -> per-thread vmcnt(0)
//   drain -> S2 -> flag store. Consumer: poll -> S3 -> sc0/sc1 h loads.
// block = (rg: 16 rows) x (cg: 8 cells); 4 x 64 = 256 blocks x 512 thr.
// bf16-split MFMA (AhBh+AhBl+AlBh), W-frags in regs, linear frag staging.

#define TT      1024
#define BB      64
#define II      256
#define HH      512
#define G4H     2048
#define RPB     16
#define NRG     4
#define NCG     64
#define THREADS 512

typedef short  bf16x8 __attribute__((ext_vector_type(8)));
typedef float  f32x4  __attribute__((ext_vector_type(4)));

__device__ __forceinline__ unsigned int cvtpk_bf16(float a, float b) {
    unsigned int r;
    asm volatile("v_cvt_pk_bf16_f32 %0, %1, %2" : "=v"(r) : "v"(a), "v"(b));
    return r;   // lo16 = bf16(a), hi16 = bf16(b), RNE
}

__device__ __forceinline__ void coh_load4_f4(const float* p0, const float* p1,
                                             const float* p2, const float* p3,
                                             float4& a, float4& b,
                                             float4& c, float4& d) {
    asm volatile(
        "global_load_dwordx4 %0, %4, off sc0 sc1\n\t"
        "global_load_dwordx4 %1, %5, off sc0 sc1\n\t"
        "global_load_dwordx4 %2, %6, off sc0 sc1\n\t"
        "global_load_dwordx4 %3, %7, off sc0 sc1\n\t"
        "s_waitcnt vmcnt(0)"
        : "=&v"(a), "=&v"(b), "=&v"(c), "=&v"(d)
        : "v"(p0), "v"(p1), "v"(p2), "v"(p3)
        : "memory");
}
__device__ __forceinline__ void coh_store_f(float* p, float v) {
    asm volatile("global_store_dword %0, %1, off sc0 sc1"
                 :: "v"(p), "v"(v) : "memory");
}
__device__ __forceinline__ void coh_store_u(unsigned int* p, unsigned int v) {
    asm volatile("global_store_dword %0, %1, off sc0 sc1"
                 :: "v"(p), "v"(v) : "memory");
}
__device__ __forceinline__ float fast_tanh(float v) {
    const float e = __expf(-2.0f * fabsf(v));
    const float r = (1.0f - e) / (1.0f + e);
    return v < 0.0f ? -r : r;
}
__device__ __forceinline__ float sigm(float v) {
    return 1.0f / (1.0f + __expf(-v));
}

// convert 8 consecutive k-elements of one fragment into hi/lo bf16x8
__device__ __forceinline__ void cvt_frag(float4 v0, float4 v1,
                                         uint4& hi, uint4& lo) {
    hi.x = cvtpk_bf16(v0.x, v0.y);
    hi.y = cvtpk_bf16(v0.z, v0.w);
    hi.z = cvtpk_bf16(v1.x, v1.y);
    hi.w = cvtpk_bf16(v1.z, v1.w);
    lo.x = cvtpk_bf16(v0.x - __uint_as_float(hi.x << 16),
                      v0.y - __uint_as_float(hi.x & 0xffff0000u));
    lo.y = cvtpk_bf16(v0.z - __uint_as_float(hi.y << 16),
                      v0.w - __uint_as_float(hi.y & 0xffff0000u));
    lo.z = cvtpk_bf16(v1.x - __uint_as_float(hi.z << 16),
                      v1.y - __uint_as_float(hi.z & 0xffff0000u));
    lo.w = cvtpk_bf16(v1.z - __uint_as_float(hi.w << 16),
                      v1.w - __uint_as_float(hi.w & 0xffff0000u));
}

__global__ void init_flags(unsigned int* f) { f[threadIdx.x] = 0; }

__global__ __launch_bounds__(THREADS) void lstm_persist(
    const float* __restrict__ x,    // [T][B][I]
    const float* __restrict__ Wi,   // [I][4H]
    const float* __restrict__ Wh,   // [H][4H]
    const float* __restrict__ bi,   // [4H]
    const float* __restrict__ bh,   // [4H]
    const float* __restrict__ h0p,  // [B][H]
    const float* __restrict__ c0p,  // [B][H]
    float* __restrict__ out,        // [T][B][H]
    unsigned int* __restrict__ flags) // [NRG*NCG*4], 16B stride, pre-zeroed
{
    const int tid   = threadIdx.x;
    const int cg    = blockIdx.x & 63;
    const int rg    = blockIdx.x >> 6;
    const int row0  = rg * RPB;
    const int cell0 = cg * 8;
    const int wv    = tid >> 6;
    const int lane  = tid & 63;
    const int n2    = wv >> 2;            // N-tile (cols 16*n2..)
    const int k4    = wv & 3;             // K-chunk

    __shared__ uint4 aFH[24 * 64];        // 24,576 B  A hi frags
    __shared__ uint4 aFL[24 * 64];        // 24,576 B  A lo
    __shared__ float red[8 * 64 * 4];     //  8,192 B  per-wave C partials
    __shared__ float c_lds[RPB][8];       //    512 B

    const int s_ls = tid & 63;
    const int s_r  = s_ls & 15;
    const int s_kb = (tid >> 6) * 32 + ((s_ls >> 4) & 3) * 8;

    // ---- one-time: W fragments -> registers (6 kk slots x hi/lo) ----
    bf16x8 wH[6], wL[6];
    {
        const int col = n2 * 16 + (lane & 15);
        const int J   = (col >> 3) * HH + cell0 + (col & 7);
        #pragma unroll
        for (int s = 0; s < 6; ++s) {
            const int kk = (s < 2) ? (k4 * 2 + s) : (8 + k4 * 4 + (s - 2));
            const int kb = kk * 32 + (lane >> 4) * 8;
            float w[8];
            #pragma unroll
            for (int e = 0; e < 8; ++e) {
                const int k = kb + e;
                w[e] = (k < II) ? Wi[(size_t)k * G4H + J]
                                : Wh[(size_t)(k - II) * G4H + J];
            }
            uint4 hi, lo;
            cvt_frag(make_float4(w[0], w[1], w[2], w[3]),
                     make_float4(w[4], w[5], w[6], w[7]), hi, lo);
            wH[s] = *(bf16x8*)&hi;
            wL[s] = *(bf16x8*)&lo;
        }
    }

    // ---- update-role constants (threads 0..127) ----
    float b4[4];
    if (tid < 128) {
        const int r = tid >> 3, m8 = tid & 7;
        #pragma unroll
        for (int g = 0; g < 4; ++g)
            b4[g] = bi[g * HH + cell0 + m8] + bh[g * HH + cell0 + m8];
        c_lds[r][m8] = c0p[(size_t)(row0 + r) * HH + cell0 + m8];
    }

    // ---- prologue: stage x_0 and h0 fragments (linear writes) ----
    {
        const float* xr = x + (size_t)(row0 + s_r) * II + s_kb;
        uint4 hi, lo;
        cvt_frag(*(const float4*)xr, *(const float4*)(xr + 4), hi, lo);
        aFH[tid] = hi; aFL[tid] = lo;

        const float* hr = h0p + (size_t)(row0 + s_r) * HH + s_kb;
        cvt_frag(*(const float4*)hr, *(const float4*)(hr + 4), hi, lo);
        aFH[512 + tid] = hi; aFL[512 + tid] = lo;
        cvt_frag(*(const float4*)(hr + 256), *(const float4*)(hr + 260), hi, lo);
        aFH[1024 + tid] = hi; aFL[1024 + tid] = lo;
    }
    __syncthreads();

    // ---- x-MFMA for t=0 ----
    f32x4 acc = {0.f, 0.f, 0.f, 0.f};
    #pragma unroll
    for (int q = 0; q < 2; ++q) {
        const int kk = k4 * 2 + q;
        const bf16x8 ah = *(const bf16x8*)&aFH[kk * 64 + lane];
        const bf16x8 al = *(const bf16x8*)&aFL[kk * 64 + lane];
        acc = __builtin_amdgcn_mfma_f32_16x16x32_bf16(ah, wH[q], acc, 0, 0, 0);
        acc = __builtin_amdgcn_mfma_f32_16x16x32_bf16(ah, wL[q], acc, 0, 0, 0);
        acc = __builtin_amdgcn_mfma_f32_16x16x32_bf16(al, wH[q], acc, 0, 0, 0);
    }

    unsigned int* myflag   = flags + (rg * NCG + cg) * 4;
    unsigned int* pollbase = flags + (rg * NCG + lane) * 4;  // wave0: lane=cg

    for (int t = 0; t < TT; ++t) {
        const bool more = (t + 1 < TT);

        // ---- issue x_{t+1} loads early ----
        float4 xv0, xv1;
        if (more) {
            const float* xr = x + ((size_t)(t + 1) * BB + row0 + s_r) * II + s_kb;
            xv0 = *(const float4*)xr;
            xv1 = *(const float4*)(xr + 4);
        }

        // ---- h-MFMA, acc carries x part ----
        #pragma unroll
        for (int q = 0; q < 4; ++q) {
            const int kk = 8 + k4 * 4 + q;
            const bf16x8 ah = *(const bf16x8*)&aFH[kk * 64 + lane];
            const bf16x8 al = *(const bf16x8*)&aFL[kk * 64 + lane];
            acc = __builtin_amdgcn_mfma_f32_16x16x32_bf16(ah, wH[2 + q], acc, 0, 0, 0);
            acc = __builtin_amdgcn_mfma_f32_16x16x32_bf16(ah, wL[2 + q], acc, 0, 0, 0);
            acc = __builtin_amdgcn_mfma_f32_16x16x32_bf16(al, wH[2 + q], acc, 0, 0, 0);
        }

        // ---- publish C partial; stage x_{t+1} ----
        ((f32x4*)red)[wv * 64 + lane] = acc;
        if (more) {
            uint4 hi, lo;
            cvt_frag(xv0, xv1, hi, lo);
            aFH[tid] = hi; aFL[tid] = lo;
        }
        __syncthreads();                        // S1

        // ---- cell update (threads 0..127) ----
        if (tid < 128) {
            const int r = tid >> 3, m8 = tid & 7;
            const int lane_c_base = 16 * (r >> 2);
            const int reg = r & 3;
            float g4[4];
            #pragma unroll
            for (int g = 0; g < 4; ++g) {
                const int col = g * 8 + m8;
                const int nn  = col >> 4, cl = col & 15;
                const int lc  = cl + lane_c_base;
                float s = b4[g];
                #pragma unroll
                for (int p = 0; p < 4; ++p)
                    s += red[((nn * 4 + p) * 64 + lc) * 4 + reg];
                g4[g] = s;
            }
            const float ig = sigm(g4[0]);
            const float fg = sigm(g4[1]);
            const float gg = fast_tanh(g4[2]);
            const float og = sigm(g4[3]);
            const float cn = fg * c_lds[r][m8] + ig * gg;
            c_lds[r][m8] = cn;
            coh_store_f(out + ((size_t)t * BB + row0 + r) * HH + cell0 + m8,
                        og * fast_tanh(cn));
        }

        // ---- release: drain h stores, then set epoch flag ----
        asm volatile("s_waitcnt vmcnt(0) lgkmcnt(0)" ::: "memory");
        __syncthreads();                        // S2
        if (more) {
            if (tid == 0) coh_store_u(myflag, (unsigned int)(t + 1));

            // ---- window: x-MFMA for t+1 ----
            acc = (f32x4){0.f, 0.f, 0.f, 0.f};
            #pragma unroll
            for (int q = 0; q < 2; ++q) {
                const int kk = k4 * 2 + q;
                const bf16x8 ah = *(const bf16x8*)&aFH[kk * 64 + lane];
                const bf16x8 al = *(const bf16x8*)&aFL[kk * 64 + lane];
                acc = __builtin_amdgcn_mfma_f32_16x16x32_bf16(ah, wH[q], acc, 0, 0, 0);
                acc = __builtin_amdgcn_mfma_f32_16x16x32_bf16(ah, wL[q], acc, 0, 0, 0);
                acc = __builtin_amdgcn_mfma_f32_16x16x32_bf16(al, wH[q], acc, 0, 0, 0);
            }

            // ---- wave0: parallel poll of all 64 flags (lane = cg) ----
            if (wv == 0) {
                const unsigned int tgt = (unsigned int)(t + 1);
                for (;;) {
                    const unsigned int v =
                        __hip_atomic_load(pollbase, __ATOMIC_RELAXED,
                                          __HIP_MEMORY_SCOPE_AGENT);
                    if (__all(v >= tgt)) break;
                    __builtin_amdgcn_s_sleep(1);
                }
            }
            __syncthreads();                    // S3

            // ---- load h_t (coherent) -> frags tid+512, tid+1024 ----
            {
                const float* hr = out + (size_t)t * BB * HH
                                  + (size_t)(row0 + s_r) * HH + s_kb;
                float4 v0, v1, v2, v3;
                coh_load4_f4(hr, hr + 4, hr + 256, hr + 260, v0, v1, v2, v3);
                uint4 hi, lo;
                cvt_frag(v0, v1, hi, lo);
                aFH[512 + tid] = hi; aFL[512 + tid] = lo;
                cvt_frag(v2, v3, hi, lo);
                aFH[1024 + tid] = hi; aFL[1024 + tid] = lo;
            }
            __syncthreads();                    // S4
        }
    }
}

extern "C" void kernel_launch(void* const* d_in, const int* in_sizes, int n_in,
                              void* d_out, int out_size, void* d_ws, size_t ws_size,
                              hipStream_t stream) {
    const float* x  = (const float*)d_in[0];
    const float* Wi = (const float*)d_in[1];
    const float* Wh = (const float*)d_in[2];
    const float* bi = (const float*)d_in[3];
    const float* bh = (const float*)d_in[4];
    const float* h0 = (const float*)d_in[5];
    const float* c0 = (const float*)d_in[6];
    float* out = (float*)d_out;
    unsigned int* flags = (unsigned int*)d_ws;   // 1024 uints = 4 KB

    init_flags<<<1, 1024, 0, stream>>>(flags);

    void* args[] = { (void*)&x, (void*)&Wi, (void*)&Wh, (void*)&bi,
                     (void*)&bh, (void*)&h0, (void*)&c0, (void*)&out,
                     (void*)&flags };
    hipError_t e = hipLaunchCooperativeKernel((const void*)lstm_persist,
                                              dim3(NRG * NCG), dim3(THREADS),
                                              args, 0, stream);
    if (e != hipSuccess) {
        (void)hipGetLastError();
        lstm_persist<<<dim3(NRG * NCG), dim3(THREADS), 0, stream>>>(
            x, Wi, Wh, bi, bh, h0, c0, out, flags);
    }
}